// Round 8
// baseline (299.730 us; speedup 1.0000x reference)
//
#include <hip/hip_runtime.h>
#include <hip/hip_fp16.h>

#define N_NODES 100000
#define IN_DIM 256
#define OUT_DIM 64
#define NT 782                 // dst/src tiles of 128 nodes
#define NB 256                 // binning blocks
#define SCHUNK 4096            // scan chunk: 256 threads * 16
#define SB ((NT * NB + SCHUNK - 1) / SCHUNK)   // 49 scan chunks per array
#define SCAN_M (NT * NB)       // 200192

typedef _Float16 half8 __attribute__((ext_vector_type(8)));
typedef float f32x4 __attribute__((ext_vector_type(4)));

// ---------------- pass 1: per-block LDS histograms of dst>>7 and src>>7 ----------------
__global__ __launch_bounds__(256) void count_kernel(const int* __restrict__ src,
                                                    const int* __restrict__ dst,
                                                    int* __restrict__ CD, int* __restrict__ CS,
                                                    int E, int chunk) {
    __shared__ int hd[NT], hs[NT];
    const int t = threadIdx.x, blk = blockIdx.x;
    for (int i = t; i < NT; i += 256) { hd[i] = 0; hs[i] = 0; }
    __syncthreads();
    const int lo = blk * chunk;
    int hi = lo + chunk; if (hi > E) hi = E;
    for (int i = lo + t; i < hi; i += 256) {
        atomicAdd(&hd[dst[i] >> 7], 1);
        atomicAdd(&hs[src[i] >> 7], 1);
    }
    __syncthreads();
    for (int i = t; i < NT; i += 256) {
        CD[i * NB + blk] = hd[i];
        CS[i * NB + blk] = hs[i];
    }
}

// ---------------- pass 2: chunk-local exclusive scan of CD and CS (in place) ----------------
// writes RAW chunk sums to BSD/BSS (consumers re-scan the 49 sums themselves)
__global__ __launch_bounds__(256) void scan_blocks_kernel(int* __restrict__ CD, int* __restrict__ CS,
                                                          int* __restrict__ BSD, int* __restrict__ BSS) {
    int cid = blockIdx.x;
    int* arr; int* bs;
    if (cid < SB) { arr = CD; bs = BSD; } else { arr = CS; bs = BSS; cid -= SB; }
    const int t = threadIdx.x;
    const int base = cid * SCHUNK + t * 16;
    int pre[16];
    int s = 0;
#pragma unroll
    for (int r = 0; r < 16; ++r) {
        int v = (base + r < SCAN_M) ? arr[base + r] : 0;
        pre[r] = s; s += v;
    }
    const int lane = t & 63;
    int incl = s;
#pragma unroll
    for (int off = 1; off < 64; off <<= 1) {
        int y = __shfl_up(incl, off);
        if (lane >= off) incl += y;
    }
    int wave_excl = incl - s;
    __shared__ int wtot[4];
    if (lane == 63) wtot[t >> 6] = incl;
    __syncthreads();
    int woff = 0;
    for (int w = 0; w < (t >> 6); ++w) woff += wtot[w];
    int bexcl = woff + wave_excl;
#pragma unroll
    for (int r = 0; r < 16; ++r)
        if (base + r < SCAN_M) arr[base + r] = bexcl + pre[r];
    if (t == 0) bs[cid] = wtot[0] + wtot[1] + wtot[2] + wtot[3];
}

// helper: waves 0/1 exclusive-scan the 49 raw chunk sums into LDS
__device__ __forceinline__ void scan_chunk_sums(const int* __restrict__ BSD,
                                                const int* __restrict__ BSS,
                                                int* sBSD, int* sBSS, int t) {
    if (t < 128) {
        const int lane = t & 63;
        const int* bs = (t < 64) ? BSD : BSS;
        int* sb = (t < 64) ? sBSD : sBSS;
        int v = (lane < SB) ? bs[lane] : 0;
        int incl = v;
#pragma unroll
        for (int off = 1; off < 64; off <<= 1) {
            int y = __shfl_up(incl, off);
            if (lane >= off) incl += y;
        }
        if (lane < SB) sb[lane] = incl - v;
    }
}

// ---------------- pass 3: deterministic scatter into dst-binned ints + src-binned bytes ----------------
__global__ __launch_bounds__(256) void scatter_kernel(const int* __restrict__ src,
                                                      const int* __restrict__ dst,
                                                      const int* __restrict__ CD, const int* __restrict__ CS,
                                                      const int* __restrict__ BSD, const int* __restrict__ BSS,
                                                      int* __restrict__ binnedD,
                                                      unsigned char* __restrict__ srcb,
                                                      int E, int chunk) {
    __shared__ int curD[NT], curS[NT];
    __shared__ int sBSD[SB], sBSS[SB];
    const int t = threadIdx.x, blk = blockIdx.x;
    scan_chunk_sums(BSD, BSS, sBSD, sBSS, t);
    __syncthreads();
    for (int i = t; i < NT; i += 256) {
        int idx = i * NB + blk;
        curD[i] = CD[idx] + sBSD[idx >> 12];
        curS[i] = CS[idx] + sBSS[idx >> 12];
    }
    __syncthreads();
    const int lo = blk * chunk;
    int hi = lo + chunk; if (hi > E) hi = E;
    for (int i = lo + t; i < hi; i += 256) {
        int s = src[i], d = dst[i];
        int p = atomicAdd(&curD[d >> 7], 1);
        binnedD[p] = (s << 7) | (d & 127);
        int ps = atomicAdd(&curS[s >> 7], 1);
        srcb[ps] = (unsigned char)(s & 127);
    }
}

// ---------------- pass 4: per-tile CSR-ify (dst) + deg_out histogram (src) ----------------
__global__ __launch_bounds__(256) void tile_kernel(const int* __restrict__ CD, const int* __restrict__ CS,
                                                   const int* __restrict__ BSD, const int* __restrict__ BSS,
                                                   const int* __restrict__ binnedD,
                                                   const unsigned char* __restrict__ srcb,
                                                   int* __restrict__ csr,
                                                   int* __restrict__ offs, int* __restrict__ cnt,
                                                   int* __restrict__ deg_out, int E) {
    __shared__ int h[128], cur[128];
    __shared__ int w0tot;
    __shared__ int sBSD[SB], sBSS[SB];
    const int bin = blockIdx.x, t = threadIdx.x, lane = t & 63;
    const int i0 = bin * NB;

    scan_chunk_sums(BSD, BSS, sBSD, sBSS, t);
    if (t < 128) h[t] = 0;
    __syncthreads();

    // ---- dst phase: histogram 128 nodes, scan, write offs/cnt, place CSR ----
    const int base = CD[i0] + sBSD[i0 >> 12];
    const int next = (bin + 1 < NT) ? (CD[i0 + NB] + sBSD[(i0 + NB) >> 12]) : E;
    const int m = next - base;
    for (int k = t; k < m; k += 256) atomicAdd(&h[binnedD[base + k] & 127], 1);
    __syncthreads();
    int v = (t < 128) ? h[t] : 0;
    int incl = v;
#pragma unroll
    for (int off = 1; off < 64; off <<= 1) {
        int y = __shfl_up(incl, off);
        if (lane >= off) incl += y;
    }
    if (t == 63) w0tot = incl;
    __syncthreads();
    int excl = incl - v + ((t >= 64 && t < 128) ? w0tot : 0);
    if (t < 128) {
        cur[t] = excl;
        int node = bin * 128 + t;
        if (node < N_NODES) { offs[node] = base + excl; cnt[node] = v; }
    }
    __syncthreads();
    for (int k = t; k < m; k += 256) {
        int rec = binnedD[base + k];
        int p = atomicAdd(&cur[rec & 127], 1);
        csr[base + p] = rec >> 7;
    }

    // ---- src phase: histogram the byte stream -> deg_out ----
    __syncthreads();
    if (t < 128) h[t] = 0;
    __syncthreads();
    const int sb = CS[i0] + sBSS[i0 >> 12];
    const int sn = (bin + 1 < NT) ? (CS[i0 + NB] + sBSS[(i0 + NB) >> 12]) : E;
    const int sm = sn - sb;
    for (int k = t; k < sm; k += 256) atomicAdd(&h[srcb[sb + k]], 1);
    __syncthreads();
    if (t < 128) {
        int node = bin * 128 + t;
        if (node < N_NODES) deg_out[node] = h[t];
    }
}

// ---------------- MFMA GEMM, A direct-from-global: x = fp16(h) @ fp16(W), row-norm in epilogue --------
// 64 rows/block, 4 waves x 16 rows. W staged ONCE in LDS fp16 [n][k] (pad 8 -> 2-way banks, free).
// K-loop has NO barriers: per step each lane loads 2 float4 of its A row (fragment order),
// converts to fp16, 4 ds_read_b128 B frags, 4 MFMAs. 16 independent global loads/lane total.
#define B_LD 264
__global__ __launch_bounds__(256) void gemm_kernel(const float* __restrict__ hmat,
                                                   const float* __restrict__ W,
                                                   const int* __restrict__ deg_out,
                                                   __half* __restrict__ xh) {
    __shared__ _Float16 sB[64 * B_LD];   // 33.8 KB
    const int t = threadIdx.x;
    const int lane = t & 63;
    const int w = t >> 6;
    const int row0 = blockIdx.x * 64;

    // stage W (transposed to [n][k]) once: 4096 float4, 16 per thread
#pragma unroll
    for (int it = 0; it < 16; ++it) {
        int f = t + it * 256;
        int k = f >> 4;              // 16 float4 per k-row of W
        int n4 = (f & 15) * 4;
        float4 v = *(const float4*)(W + (size_t)k * OUT_DIM + n4);
        sB[(n4 + 0) * B_LD + k] = (_Float16)v.x;
        sB[(n4 + 1) * B_LD + k] = (_Float16)v.y;
        sB[(n4 + 2) * B_LD + k] = (_Float16)v.z;
        sB[(n4 + 3) * B_LD + k] = (_Float16)v.w;
    }
    __syncthreads();

    const int m16 = lane & 15;
    const int kq = lane >> 4;                 // 0..3
    int grow = row0 + w * 16 + m16;
    const float* arow = hmat + (size_t)(grow < N_NODES ? grow : N_NODES - 1) * IN_DIM;

    f32x4 acc[4] = {{0.f,0.f,0.f,0.f},{0.f,0.f,0.f,0.f},{0.f,0.f,0.f,0.f},{0.f,0.f,0.f,0.f}};

#pragma unroll
    for (int kb = 0; kb < 8; ++kb) {
        const int koff = kb * 32 + kq * 8;
        float4 alo = *(const float4*)(arow + koff);
        float4 ahi = *(const float4*)(arow + koff + 4);
        _Float16 af[8];
        af[0] = (_Float16)alo.x; af[1] = (_Float16)alo.y;
        af[2] = (_Float16)alo.z; af[3] = (_Float16)alo.w;
        af[4] = (_Float16)ahi.x; af[5] = (_Float16)ahi.y;
        af[6] = (_Float16)ahi.z; af[7] = (_Float16)ahi.w;
        half8 a = *(half8*)af;
#pragma unroll
        for (int ni = 0; ni < 4; ++ni) {
            half8 b = *(const half8*)&sB[(ni * 16 + m16) * B_LD + koff];
            acc[ni] = __builtin_amdgcn_mfma_f32_16x16x32_f16(a, b, acc[ni], 0, 0, 0);
        }
    }

    // epilogue: C/D col=lane&15, row=(lane>>4)*4+reg; row-scale by rsqrt(deg_out)
    const int rq = kq * 4;
    float nrm[4];
#pragma unroll
    for (int r = 0; r < 4; ++r) {
        int row = row0 + w * 16 + rq + r;
        int d = (row < N_NODES) ? deg_out[row] : 1;
        nrm[r] = rsqrtf((float)(d < 1 ? 1 : d));
    }
#pragma unroll
    for (int ni = 0; ni < 4; ++ni) {
        int col = ni * 16 + m16;
#pragma unroll
        for (int r = 0; r < 4; ++r) {
            int row = row0 + w * 16 + rq + r;
            if (row < N_NODES)
                xh[(size_t)row * OUT_DIM + col] = __float2half(acc[ni][r] * nrm[r]);
        }
    }
}

// ---------------- aggregate: one wave per node, 8 lanes x 16B per edge row ----------------
__global__ __launch_bounds__(256) void aggregate_kernel(const int* __restrict__ offs,
                                                        const int* __restrict__ cnt,
                                                        const int* __restrict__ csr,
                                                        const __half* __restrict__ xh,
                                                        const float* __restrict__ b,
                                                        float* __restrict__ out) {
    const int t = threadIdx.x;
    const int lane = t & 63;
    const int wid = t >> 6;
    const int node = blockIdx.x * 4 + wid;          // 25000*4 == N_NODES exactly
    const int g = lane >> 3;
    const int c = lane & 7;

    const int start = offs[node];
    const int n = cnt[node];

    float acc[8] = {0.f, 0.f, 0.f, 0.f, 0.f, 0.f, 0.f, 0.f};
    for (int base = 0; base < n; base += 64) {
        int k = base + lane;
        int sidx = (k < n) ? csr[start + k] : 0;
        int m = n - base; if (m > 64) m = 64;
        for (int rb = 0; rb < m; rb += 32) {
            uint4 raw[4]; float wq[4];
#pragma unroll
            for (int q = 0; q < 4; ++q) {
                int e = rb + 8 * q + g;              // <= 63 always
                int s = __shfl(sidx, e);
                bool val = e < m;
                s = val ? s : 0;
                wq[q] = val ? 1.f : 0.f;
                raw[q] = *(const uint4*)(xh + (size_t)s * OUT_DIM + 8 * c);
            }
#pragma unroll
            for (int q = 0; q < 4; ++q) {
                const __half2* hp = (const __half2*)&raw[q];
#pragma unroll
                for (int p = 0; p < 4; ++p) {
                    float2 f = __half22float2(hp[p]);
                    acc[2 * p]     = fmaf(wq[q], f.x, acc[2 * p]);
                    acc[2 * p + 1] = fmaf(wq[q], f.y, acc[2 * p + 1]);
                }
            }
        }
    }

#pragma unroll
    for (int off = 8; off < 64; off <<= 1) {
#pragma unroll
        for (int p = 0; p < 8; ++p)
            acc[p] += __shfl_xor(acc[p], off);
    }

    if (g == 0) {   // lanes 0..7 hold full sums for cols c*8..c*8+7
        float nrm = rsqrtf((float)(n < 1 ? 1 : n));
        float4 bv0 = *(const float4*)&b[c * 8];
        float4 bv1 = *(const float4*)&b[c * 8 + 4];
        float4 r0, r1;
        r0.x = fmaxf(fmaf(acc[0], nrm, bv0.x), 0.f);
        r0.y = fmaxf(fmaf(acc[1], nrm, bv0.y), 0.f);
        r0.z = fmaxf(fmaf(acc[2], nrm, bv0.z), 0.f);
        r0.w = fmaxf(fmaf(acc[3], nrm, bv0.w), 0.f);
        r1.x = fmaxf(fmaf(acc[4], nrm, bv1.x), 0.f);
        r1.y = fmaxf(fmaf(acc[5], nrm, bv1.y), 0.f);
        r1.z = fmaxf(fmaf(acc[6], nrm, bv1.z), 0.f);
        r1.w = fmaxf(fmaf(acc[7], nrm, bv1.w), 0.f);
        float4* orow = (float4*)(out + (size_t)node * OUT_DIM + c * 8);
        orow[0] = r0;
        orow[1] = r1;
    }
}

extern "C" void kernel_launch(void* const* d_in, const int* in_sizes, int n_in,
                              void* d_out, int out_size, void* d_ws, size_t ws_size,
                              hipStream_t stream) {
    const float* h   = (const float*)d_in[0];
    const int*   src = (const int*)d_in[1];
    const int*   dst = (const int*)d_in[2];
    const float* W   = (const float*)d_in[3];
    const float* b   = (const float*)d_in[4];
    float* out = (float*)d_out;
    const int E = in_sizes[1];
    const int chunk = (E + NB - 1) / NB;

    // workspace layout (16B aligned), total ~30 MB; everything is written before read
    char* ws = (char*)d_ws;
    int*           CD      = (int*)(ws);                    // NT*NB ints (800,768 B)
    int*           CS      = (int*)(ws + 800768);           // NT*NB ints
    int*           BSD     = (int*)(ws + 1601536);          // SB ints (padded 256 B)
    int*           BSS     = (int*)(ws + 1601792);          // SB ints
    int*           binnedD = (int*)(ws + 1602048);          // E ints  (6.4 MB)
    unsigned char* srcb    = (unsigned char*)(ws + 8002048);// E bytes (1.6 MB)
    int*           csr     = (int*)(ws + 9602048);          // E ints  (6.4 MB)
    int*           offs    = (int*)(ws + 16002048);         // N ints
    int*           cntA    = (int*)(ws + 16402048);         // N ints
    int*           deg_out = (int*)(ws + 16802048);         // N ints
    __half*        xh      = (__half*)(ws + 17202048);      // N*64 halfs (12.8 MB)

    count_kernel<<<NB, 256, 0, stream>>>(src, dst, CD, CS, E, chunk);
    scan_blocks_kernel<<<2 * SB, 256, 0, stream>>>(CD, CS, BSD, BSS);
    scatter_kernel<<<NB, 256, 0, stream>>>(src, dst, CD, CS, BSD, BSS, binnedD, srcb, E, chunk);
    tile_kernel<<<NT, 256, 0, stream>>>(CD, CS, BSD, BSS, binnedD, srcb, csr, offs, cntA, deg_out, E);
    gemm_kernel<<<(N_NODES + 63) / 64, 256, 0, stream>>>(h, W, deg_out, xh);
    aggregate_kernel<<<N_NODES / 4, 256, 0, stream>>>(offs, cntA, csr, xh, b, out);
}